// Round 1
// baseline (318.066 us; speedup 1.0000x reference)
//
#include <hip/hip_runtime.h>
#include <stdint.h>

// Problem constants: x[B=32][N=8192][D=64] fp32 -> out[B][D][D][D] fp32
#define B_SZ 32
#define N_SZ 8192
#define D_SZ 64

typedef _Float16 half8 __attribute__((ext_vector_type(8)));
typedef float floatx4 __attribute__((ext_vector_type(4)));

#define AS1 __attribute__((address_space(1)))
#define AS3 __attribute__((address_space(3)))

// ---------------------------------------------------------------------------
// Kernel 1: per-batch column sums (for mean). grid = 32 b * 8 slabs.
// ---------------------------------------------------------------------------
__global__ __launch_bounds__(256) void tp_mean_kernel(const float* __restrict__ x,
                                                      float* __restrict__ sums) {
    const int b    = blockIdx.x >> 3;
    const int slab = blockIdx.x & 7;
    const int d    = threadIdx.x & 63;
    const int nn   = threadIdx.x >> 6;   // 0..3
    const float* xb = x + (size_t)b * (N_SZ * D_SZ);
    const int n0 = slab * 1024;
    float s = 0.f;
    for (int n = n0 + nn; n < n0 + 1024; n += 4)
        s += xb[n * D_SZ + d];
    __shared__ float red[256];
    red[threadIdx.x] = s;
    __syncthreads();
    if (threadIdx.x < 64) {
        float t = red[threadIdx.x] + red[threadIdx.x + 64] +
                  red[threadIdx.x + 128] + red[threadIdx.x + 192];
        atomicAdd(&sums[b * 64 + threadIdx.x], t);
    }
}

// ---------------------------------------------------------------------------
// Kernel 2: center, cast to fp16, write transposed + chunk-swizzled layout.
// Layout: xcS[b][tile=n/64][d][cc'] where each 16B chunk cc' holds 8 n-values;
// data chunk cc (n = tile*64 + cc*8 ..+8) of row d is stored at cc' = cc^(d&7).
// One workgroup per (b, tile). grid = 32*128.
// ---------------------------------------------------------------------------
__global__ __launch_bounds__(256) void tp_transpose_kernel(const float* __restrict__ x,
                                                           const float* __restrict__ sums,
                                                           _Float16* __restrict__ xcS) {
    const int b    = blockIdx.x >> 7;
    const int tile = blockIdx.x & 127;
    __shared__ float mean_s[64];
    __shared__ __align__(16) _Float16 tileT[64][72];   // 144B row stride (16B-aligned)

    if (threadIdx.x < 64)
        mean_s[threadIdx.x] = sums[b * 64 + threadIdx.x] * (1.0f / (float)N_SZ);
    __syncthreads();

    // read phase: thread -> (n-row r, d-quarter q), 16 floats
    const int r = threadIdx.x >> 2;
    const int q = threadIdx.x & 3;
    const float* src = x + (size_t)b * (N_SZ * D_SZ) + (size_t)(tile * 64 + r) * D_SZ + q * 16;
    float4 v0 = ((const float4*)src)[0];
    float4 v1 = ((const float4*)src)[1];
    float4 v2 = ((const float4*)src)[2];
    float4 v3 = ((const float4*)src)[3];
    float vv[16];
    vv[0]=v0.x; vv[1]=v0.y; vv[2]=v0.z; vv[3]=v0.w;
    vv[4]=v1.x; vv[5]=v1.y; vv[6]=v1.z; vv[7]=v1.w;
    vv[8]=v2.x; vv[9]=v2.y; vv[10]=v2.z; vv[11]=v2.w;
    vv[12]=v3.x; vv[13]=v3.y; vv[14]=v3.z; vv[15]=v3.w;
#pragma unroll
    for (int i = 0; i < 16; i++) {
        int d = q * 16 + i;
        tileT[d][r] = (_Float16)(vv[i] - mean_s[d]);
    }
    __syncthreads();

    // write phase: 512 16B chunks per tile, 2 per thread, fully coalesced
    _Float16* dstb = xcS + (size_t)b * (N_SZ * D_SZ) + (size_t)tile * 4096;
#pragma unroll
    for (int c = 0; c < 2; c++) {
        int G   = c * 256 + threadIdx.x;
        int d   = G >> 3;
        int ccp = G & 7;
        int cc  = ccp ^ (d & 7);
        half8 val = *(const half8*)&tileT[d][cc * 8];
        *(half8*)(dstb + d * 64 + ccp * 8) = val;
    }
}

// ---------------------------------------------------------------------------
// Kernel 3: batched GEMM. wg = (e-group of 4, b). C_e[d,f] = sum_n A'[d,n]*B[n,f]
// with A'[d,n] = xc[n,d]*xc[n,e], B[n,f] = xc[n,f]. All fragments come from one
// 64x64 LDS tile (rows = d/e/f index, cols = n-chunk, 16B chunks XOR-swizzled).
// ---------------------------------------------------------------------------
__global__ __launch_bounds__(256, 2) void tp_gemm_kernel(const _Float16* __restrict__ xcS,
                                                         float* __restrict__ out) {
    const int eg  = blockIdx.x;            // 0..15
    const int b   = blockIdx.y;            // 0..31
    const int tid = threadIdx.x;
    const int lane = tid & 63;
    const int wv   = tid >> 6;             // 0..3
    const int quad = lane >> 4;            // 0..3
    const int m    = lane & 15;

    __shared__ __align__(16) _Float16 lds[4096];   // 64 rows x 64 halves (8KB)

    const _Float16* xb = xcS + (size_t)b * (N_SZ * D_SZ);

    floatx4 acc[4][4];   // [e in group][f-block]
#pragma unroll
    for (int j = 0; j < 4; j++)
#pragma unroll
        for (int fb = 0; fb < 4; fb++)
            acc[j][fb] = (floatx4){0.f, 0.f, 0.f, 0.f};

    // fragment chunk offsets (swizzled): chunk cc at row r lives at (cc^(r&7))*8
    const int c0 = ((quad)     ^ (m & 7)) * 8;     // kk = 0
    const int c1 = ((quad + 4) ^ (m & 7)) * 8;     // kk = 32
    int rowOff[4];
#pragma unroll
    for (int fb = 0; fb < 4; fb++) rowOff[fb] = (fb * 16 + m) * 64;
    const int aRow = (wv * 16 + m) * 64;
    const int e_base = eg * 4;
    int sOff[4][2];
#pragma unroll
    for (int j = 0; j < 4; j++) {
        int er = e_base + j;
        sOff[j][0] = er * 64 + (((quad)     ^ (er & 7)) * 8);
        sOff[j][1] = er * 64 + (((quad + 4) ^ (er & 7)) * 8);
    }

    for (int t = 0; t < N_SZ / 64; t++) {
        // stage one contiguous 8KB tile via async global->LDS (16B/lane)
        const _Float16* g = xb + t * 4096 + tid * 8;
        __builtin_amdgcn_global_load_lds((const AS1 void*)g,
                                         (AS3 void*)(lds + wv * 512), 16, 0, 0);
        __builtin_amdgcn_global_load_lds((const AS1 void*)(g + 2048),
                                         (AS3 void*)(lds + 2048 + wv * 512), 16, 0, 0);
        __syncthreads();
#pragma unroll
        for (int kk = 0; kk < 2; kk++) {
            const int co = kk ? c1 : c0;
            half8 R[4];
#pragma unroll
            for (int fb = 0; fb < 4; fb++)
                R[fb] = *(const half8*)(lds + rowOff[fb] + co);
            half8 A = *(const half8*)(lds + aRow + co);
#pragma unroll
            for (int j = 0; j < 4; j++) {
                half8 S  = *(const half8*)(lds + (kk ? sOff[j][1] : sOff[j][0]));
                half8 Ap = A * S;   // v_pk_mul_f16 x4
#pragma unroll
                for (int fb = 0; fb < 4; fb++)
                    acc[j][fb] = __builtin_amdgcn_mfma_f32_16x16x32_f16(
                        Ap, R[fb], acc[j][fb], 0, 0, 0);
            }
        }
        __syncthreads();
    }

    // epilogue: C/D layout col = lane&15 (f), row = quad*4+reg (d within block)
    const float invn = 1.0f / (float)N_SZ;
    float* outb = out + (size_t)b * (D_SZ * D_SZ * D_SZ);
#pragma unroll
    for (int j = 0; j < 4; j++) {
        const int e = e_base + j;
#pragma unroll
        for (int fb = 0; fb < 4; fb++) {
            const int f = fb * 16 + m;
#pragma unroll
            for (int rg = 0; rg < 4; rg++) {
                const int d = wv * 16 + quad * 4 + rg;
                outb[(size_t)d * 4096 + e * 64 + f] = acc[j][fb][rg] * invn;
            }
        }
    }
}

// ---------------------------------------------------------------------------
extern "C" void kernel_launch(void* const* d_in, const int* in_sizes, int n_in,
                              void* d_out, int out_size, void* d_ws, size_t ws_size,
                              hipStream_t stream) {
    const float* x = (const float*)d_in[0];
    float* out = (float*)d_out;

    // workspace layout: [0, 8KB) fp32 column sums; [8KB, 8KB+33.5MB) fp16 xcS
    float* sums = (float*)d_ws;
    _Float16* xcS = (_Float16*)((char*)d_ws + 8192);

    hipMemsetAsync(sums, 0, B_SZ * D_SZ * sizeof(float), stream);
    tp_mean_kernel<<<dim3(B_SZ * 8), 256, 0, stream>>>(x, sums);
    tp_transpose_kernel<<<dim3(B_SZ * (N_SZ / 64)), 256, 0, stream>>>(x, sums, xcS);
    tp_gemm_kernel<<<dim3(16, B_SZ), 256, 0, stream>>>(xcS, out);
}

// Round 3
// 191.373 us; speedup vs baseline: 1.6620x; 1.6620x over previous
//
#include <hip/hip_runtime.h>
#include <stdint.h>

// Problem: x[B=32][N=8192][D=64] fp32 -> out[B][D][D][D] fp32 (centered 3rd moment)
#define B_SZ 32
#define N_SZ 8192
#define D_SZ 64

typedef _Float16 half8 __attribute__((ext_vector_type(8)));
typedef float f32x4 __attribute__((ext_vector_type(4)));

#define AS1 __attribute__((address_space(1)))
#define AS3 __attribute__((address_space(3)))

#define MFMA16(Aop, Bop, Cop) __builtin_amdgcn_mfma_f32_16x16x32_f16(Aop, Bop, Cop, 0, 0, 0)

// ---------------------------------------------------------------------------
// Kernel 1: per-batch column sums. grid = 32 b * 32 slabs (256 n-rows each).
// ---------------------------------------------------------------------------
__global__ __launch_bounds__(256) void tp_mean_kernel(const float* __restrict__ x,
                                                      float* __restrict__ sums) {
    const int b    = blockIdx.x >> 5;
    const int slab = blockIdx.x & 31;
    const int d4   = threadIdx.x & 15;
    const int nr   = threadIdx.x >> 4;
    const float* base = x + (size_t)b * (N_SZ * D_SZ) + (size_t)(slab * 256 + nr) * D_SZ + d4 * 4;
    f32x4 s = {0.f, 0.f, 0.f, 0.f};
#pragma unroll
    for (int i = 0; i < 16; i++)
        s += *(const f32x4*)(base + i * 16 * D_SZ);
    __shared__ f32x4 red[16][16];
    red[nr][d4] = s;
    __syncthreads();
    if (threadIdx.x < 16) {
        f32x4 tot = red[0][threadIdx.x];
#pragma unroll
        for (int j = 1; j < 16; j++) tot += red[j][threadIdx.x];
        atomicAdd(&sums[b * 64 + threadIdx.x * 4 + 0], tot[0]);
        atomicAdd(&sums[b * 64 + threadIdx.x * 4 + 1], tot[1]);
        atomicAdd(&sums[b * 64 + threadIdx.x * 4 + 2], tot[2]);
        atomicAdd(&sums[b * 64 + threadIdx.x * 4 + 3], tot[3]);
    }
}

// ---------------------------------------------------------------------------
// Kernel 2: center, cast fp16, register transpose into chunk-XOR-swizzled
// layout xcS[b][tile][d][cc'] with data chunk cc stored at cc' = cc ^ (d&7).
// ---------------------------------------------------------------------------
__global__ __launch_bounds__(256) void tp_transpose_kernel(const float* __restrict__ x,
                                                           const float* __restrict__ sums,
                                                           _Float16* __restrict__ xcS) {
    const int b    = blockIdx.x >> 6;
    const int tp   = blockIdx.x & 63;
    const int t    = threadIdx.x;
    const int tile = tp * 2 + (t >> 7);
    const int r8   = (t >> 4) & 7;
    const int dq   = t & 15;

    f32x4 mean4 = *(const f32x4*)(sums + b * 64 + dq * 4) * (1.0f / (float)N_SZ);
    const float* src = x + (size_t)b * (N_SZ * D_SZ) + (size_t)(tile * 64 + r8 * 8) * D_SZ + dq * 4;
    f32x4 v[8];
#pragma unroll
    for (int i = 0; i < 8; i++)
        v[i] = *(const f32x4*)(src + i * D_SZ);

    _Float16* dstb = xcS + (size_t)b * (N_SZ * D_SZ) + (size_t)tile * 4096;
#pragma unroll
    for (int c = 0; c < 4; c++) {
        const int d   = dq * 4 + c;
        const int ccp = r8 ^ (d & 7);
        half8 o;
#pragma unroll
        for (int i = 0; i < 8; i++)
            o[i] = (_Float16)(v[i][c] - mean4[c]);
        *(half8*)(dstb + d * 64 + ccp * 8) = o;
    }
}

// ---------------------------------------------------------------------------
// Kernel 3: symmetric batched GEMM, 16x16x32 MFMA (R1-validated layouts).
// grid = (16 e-quads, 32 b). wg = 4 waves = (p in {0,1}, h in {0,1}).
// Wave (p,h) handles e in {eg*4+2p, +1} over N-half h. TWO LDS tiles (one per
// h) so each wave reads data from its own N-half (R2's bug: single mixed tile).
// Per k32-step: 4 A-row reads + 2 S reads -> 2e x 10 symmetric-block MFMAs.
// Cross-h reduction via LDS; mirrored epilogue stores.
// ---------------------------------------------------------------------------
__global__ __launch_bounds__(256, 2) void tp_gemm_kernel(const _Float16* __restrict__ xcS,
                                                         float* __restrict__ out) {
    const int eg   = blockIdx.x;          // 0..15
    const int b    = blockIdx.y;          // 0..31
    const int tid  = threadIdx.x;
    const int lane = tid & 63;
    const int wv   = tid >> 6;            // 0..3
    const int h    = wv & 1;              // N-half
    const int p    = wv >> 1;             // e-pair within quad
    const int q    = lane >> 4;           // 0..3
    const int m    = lane & 15;
    const int e0   = eg * 4 + p * 2;

    __shared__ __align__(16) char ldsraw[40960];
    _Float16* tileL = (_Float16*)ldsraw;   // [h][4096] halves = 16 KB staging
    float*    redL  = (float*)ldsraw;      // 10240 floats reduction (aliased, post-loop)

    // staging: wave (p,h) loads segment p (2048 halves) of tile h each iter
    const _Float16* gbase = xcS + (size_t)b * (N_SZ * D_SZ)
                          + (size_t)h * (N_SZ / 2) * D_SZ
                          + (size_t)(p * 2048 + lane * 8);
    _Float16* lbase = tileL + h * 4096 + p * 2048;

    // fragment byte offsets within my tile; k-step ks covers k = ks*32..+32,
    // lane needs chunk c = ks*4 + q of its row r, swizzled to (c ^ (r&7)).
    const char* tb = (const char*)(tileL + h * 4096);
    int aOff[2][4], sOff[2][2];
#pragma unroll
    for (int ks = 0; ks < 2; ks++) {
        const int c = ks * 4 + q;
#pragma unroll
        for (int i = 0; i < 4; i++) {
            const int r = i * 16 + m;
            aOff[ks][i] = r * 128 + ((c ^ (r & 7)) * 16);
        }
#pragma unroll
        for (int j = 0; j < 2; j++) {
            const int e = e0 + j;
            sOff[ks][j] = e * 128 + ((c ^ (e & 7)) * 16);
        }
    }

    f32x4 acc[2][10];
#pragma unroll
    for (int ej = 0; ej < 2; ej++)
#pragma unroll
        for (int k = 0; k < 10; k++)
            acc[ej][k] = (f32x4){0.f, 0.f, 0.f, 0.f};

    for (int t = 0; t < 64; t++) {
        const _Float16* g = gbase + t * 4096;
#pragma unroll
        for (int i = 0; i < 4; i++)
            __builtin_amdgcn_global_load_lds((const AS1 void*)(g + i * 512),
                                             (AS3 void*)(lbase + i * 512), 16, 0, 0);
        __syncthreads();
#pragma unroll
        for (int ks = 0; ks < 2; ks++) {
            half8 A0 = *(const half8*)(tb + aOff[ks][0]);
            half8 A1 = *(const half8*)(tb + aOff[ks][1]);
            half8 A2 = *(const half8*)(tb + aOff[ks][2]);
            half8 A3 = *(const half8*)(tb + aOff[ks][3]);
            half8 S0 = *(const half8*)(tb + sOff[ks][0]);
            half8 S1 = *(const half8*)(tb + sOff[ks][1]);
#pragma unroll
            for (int ej = 0; ej < 2; ej++) {
                half8 S = ej ? S1 : S0;
                half8 P0 = A0 * S;   // fold xc[n,e] into A operand (v_pk_mul_f16)
                half8 P1 = A1 * S;
                half8 P2 = A2 * S;
                half8 P3 = A3 * S;
                acc[ej][0] = MFMA16(P0, A0, acc[ej][0]);
                acc[ej][1] = MFMA16(P0, A1, acc[ej][1]);
                acc[ej][2] = MFMA16(P0, A2, acc[ej][2]);
                acc[ej][3] = MFMA16(P0, A3, acc[ej][3]);
                acc[ej][4] = MFMA16(P1, A1, acc[ej][4]);
                acc[ej][5] = MFMA16(P1, A2, acc[ej][5]);
                acc[ej][6] = MFMA16(P1, A3, acc[ej][6]);
                acc[ej][7] = MFMA16(P2, A2, acc[ej][7]);
                acc[ej][8] = MFMA16(P2, A3, acc[ej][8]);
                acc[ej][9] = MFMA16(P3, A3, acc[ej][9]);
            }
        }
        __syncthreads();
    }

    // cross-h reduction: h==1 waves dump 20 f32x4/lane; h==0 waves add.
    if (h == 1) {
        float* w = redL + p * 5120 + lane * 4;
#pragma unroll
        for (int ej = 0; ej < 2; ej++)
#pragma unroll
            for (int k = 0; k < 10; k++)
                *(f32x4*)(w + (ej * 10 + k) * 256) = acc[ej][k];
    }
    __syncthreads();
    if (h == 0) {
        const float* rr = redL + p * 5120 + lane * 4;
#pragma unroll
        for (int ej = 0; ej < 2; ej++)
#pragma unroll
            for (int k = 0; k < 10; k++) {
                f32x4 w = *(const f32x4*)(rr + (ej * 10 + k) * 256);
                acc[ej][k] += w;
            }
        const float invn = 1.0f / (float)N_SZ;
        float* outb = out + (size_t)b * (D_SZ * D_SZ * D_SZ);
        // C/D layout (verified): col = lane&15 = f-within-block, row = q*4+reg
#pragma unroll
        for (int ej = 0; ej < 2; ej++) {
            const int e = e0 + ej;
            int idx = 0;
#pragma unroll
            for (int i = 0; i < 4; i++)
#pragma unroll
                for (int j = 4; j-- > 0;) {   // placeholder to keep idx math simple
                    // (real loop below)
                    (void)j; break;
                }
            // explicit upper-triangle blocks (i <= j), idx 0..9
#pragma unroll
            for (int i = 0; i < 4; i++) {
#pragma unroll
                for (int j = i; j < 4; j++, idx++) {
                    f32x4 vsc = acc[ej][idx] * invn;
                    // normal store: d = 16i + q*4 + r, f = 16j + m
#pragma unroll
                    for (int r = 0; r < 4; r++)
                        outb[(size_t)(16 * i + q * 4 + r) * 4096 + e * 64 + 16 * j + m] = vsc[r];
                    if (i != j) {
                        // mirror: d = 16j + m, f = 16i + q*4 .. +4 (contiguous)
                        *(f32x4*)&outb[(size_t)(16 * j + m) * 4096 + e * 64 + 16 * i + q * 4] = vsc;
                    }
                }
            }
        }
    }
}

// ---------------------------------------------------------------------------
extern "C" void kernel_launch(void* const* d_in, const int* in_sizes, int n_in,
                              void* d_out, int out_size, void* d_ws, size_t ws_size,
                              hipStream_t stream) {
    const float* x = (const float*)d_in[0];
    float* out = (float*)d_out;

    float* sums = (float*)d_ws;                           // 8 KB
    _Float16* xcS = (_Float16*)((char*)d_ws + 8192);      // 33.5 MB fp16

    hipMemsetAsync(sums, 0, B_SZ * D_SZ * sizeof(float), stream);
    tp_mean_kernel<<<dim3(B_SZ * 32), 256, 0, stream>>>(x, sums);
    tp_transpose_kernel<<<dim3(B_SZ * 64), 256, 0, stream>>>(x, sums, xcS);
    tp_gemm_kernel<<<dim3(16, B_SZ), 256, 0, stream>>>(xcS, out);
}